// Round 4
// baseline (543.830 us; speedup 1.0000x reference)
//
#include <hip/hip_runtime.h>
#include <math.h>

static constexpr int Bn = 8;
static constexpr int Cn = 256;
static constexpr int Sn = 16384;   // 128*128

typedef __bf16 bf16x4 __attribute__((ext_vector_type(4)));
typedef __bf16 bf16x8 __attribute__((ext_vector_type(8)));
typedef float  f32x4  __attribute__((ext_vector_type(4)));

static constexpr int TILE = 128;
static constexpr int KB   = 32;

// ---------------- shared LDS layout helpers ----------------
// Tile buffer: 128 rows x 32 bf16 (one K-chunk), zero pad, XOR chunk swizzle.
// Row = 64 B = 4 chunks of 16 B. Data chunk c of row r lives at slot c^(r&3).
__device__ __forceinline__ void split_store(__bf16* __restrict__ Hi, __bf16* __restrict__ Lo,
                                            int row, int kq, float4 v) {
  __bf16 h0 = (__bf16)v.x, h1 = (__bf16)v.y, h2 = (__bf16)v.z, h3 = (__bf16)v.w;
  int off = row * 32 + (((kq >> 1) ^ (row & 3)) << 3) + ((kq & 1) << 2);
  *(bf16x4*)&Hi[off] = (bf16x4){h0, h1, h2, h3};
  *(bf16x4*)&Lo[off] = (bf16x4){(__bf16)(v.x - (float)h0), (__bf16)(v.y - (float)h1),
                                (__bf16)(v.z - (float)h2), (__bf16)(v.w - (float)h3)};
}

__device__ __forceinline__ bf16x8 frag_ld(const __bf16* __restrict__ P, int row, int quad) {
  return *(const bf16x8*)&P[row * 32 + ((quad ^ (row & 3)) << 3)];
}

// ---------------- device-scope grid barrier (persistent-kernel fusion) ------
// Generation-counter barrier; cnt self-resets, gen is monotonic across graph
// replays. Only valid when grid <= co-resident capacity (enforced at launch
// via hipOccupancyMaxActiveBlocksPerMultiprocessor).
__device__ unsigned g_cnt[4] = {0, 0, 0, 0};
__device__ unsigned g_gen[4] = {0, 0, 0, 0};

__device__ __forceinline__ void grid_barrier(int slot) {
  __syncthreads();
  if (threadIdx.x == 0) {
    __threadfence();   // release: make this block's writes agent-visible
    unsigned my = __hip_atomic_load(&g_gen[slot], __ATOMIC_RELAXED, __HIP_MEMORY_SCOPE_AGENT);
    unsigned n  = gridDim.x;
    unsigned a  = __hip_atomic_fetch_add(&g_cnt[slot], 1u, __ATOMIC_ACQ_REL,
                                         __HIP_MEMORY_SCOPE_AGENT) + 1u;
    if (a == n) {
      __hip_atomic_store(&g_cnt[slot], 0u, __ATOMIC_RELAXED, __HIP_MEMORY_SCOPE_AGENT);
      __hip_atomic_fetch_add(&g_gen[slot], 1u, __ATOMIC_RELEASE, __HIP_MEMORY_SCOPE_AGENT);
    } else {
      while (__hip_atomic_load(&g_gen[slot], __ATOMIC_RELAXED, __HIP_MEMORY_SCOPE_AGENT) == my)
        __builtin_amdgcn_s_sleep(2);
    }
    __threadfence();   // acquire: invalidate stale L1/L2 before next phase reads
  }
  __syncthreads();
}

// ---------------- fused persistent kernel ----------------
// Phase 0: zero energy. Phase 1: symmetric Gram (split-bf16 MFMA, atomic
// partials). Phase 2: softmax (wave/row). Phase 3: y = w@v + residual.
// 1024 gram jobs: job<512 diag (ksl=512, 16 chunks), job>=512 off-diag
// (ksl=256, 8 chunks) -> every block does exactly 24 chunks at grid=512.
__global__ __launch_bounds__(256, 2) void fused_kernel(const float* __restrict__ x,
                                                       const float* __restrict__ alpha,
                                                       float* __restrict__ out,
                                                       float* __restrict__ energy) {
  __shared__ __align__(16) __bf16 Ah[TILE * 32];
  __shared__ __align__(16) __bf16 Al[TILE * 32];
  __shared__ __align__(16) __bf16 Bh[TILE * 32];
  __shared__ __align__(16) __bf16 Bl[TILE * 32];

  const int t    = threadIdx.x;           // 0..255
  const int lane = t & 63;
  const int wv   = t >> 6;
  const int wr   = wv >> 1;
  const int wc   = wv & 1;
  const int ln   = lane & 15;
  const int quad = lane >> 4;
  const int srow = t >> 3;                // staging row base 0..31
  const int skq  = t & 7;                 // float4 index within chunk

  // ---- phase 0: zero energy (B*C*C fp32 = 131072 float4) ----
  {
    const int total = (Bn * Cn * Cn) / 4;
    for (int i = blockIdx.x * 256 + t; i < total; i += gridDim.x * 256)
      *(float4*)&energy[(size_t)i * 4] = (float4){0.f, 0.f, 0.f, 0.f};
  }
  grid_barrier(0);

  // ---- phase 1: gram ----
  for (unsigned job = blockIdx.x; job < 1024; job += gridDim.x) {
    int b, ti, tj, kk, ksl;
    bool diag;
    if (job < 512) {                      // diagonal tiles: 8b x 2tiles x 32 slices
      b = job >> 6; int r = job & 63;
      diag = true; ti = tj = (r >> 5); kk = r & 31; ksl = 512;
    } else {                              // off-diag tile: 8b x 64 slices
      unsigned j2 = job - 512;
      b = j2 >> 6; kk = j2 & 63;
      diag = false; ti = 0; tj = 1; ksl = 256;
    }

    const float* vb    = x + (size_t)b * Cn * Sn;
    const float* Abase = vb + (size_t)(ti * TILE) * Sn + (size_t)kk * ksl;
    const float* Bbase = vb + (size_t)(tj * TILE) * Sn + (size_t)kk * ksl;

    float4 areg[4], breg[4];
#pragma unroll
    for (int it = 0; it < 4; it++)
      areg[it] = *(const float4*)(Abase + (size_t)(srow + it * 32) * Sn + skq * 4);
    if (!diag) {
#pragma unroll
      for (int it = 0; it < 4; it++)
        breg[it] = *(const float4*)(Bbase + (size_t)(srow + it * 32) * Sn + skq * 4);
    }

    f32x4 acc[4][4];
#pragma unroll
    for (int i = 0; i < 4; i++)
#pragma unroll
      for (int j = 0; j < 4; j++) acc[i][j] = (f32x4){0.f, 0.f, 0.f, 0.f};

    for (int kc = 0; kc < ksl; kc += KB) {
#pragma unroll
      for (int it = 0; it < 4; it++) split_store(Ah, Al, srow + it * 32, skq, areg[it]);
      if (!diag) {
#pragma unroll
        for (int it = 0; it < 4; it++) split_store(Bh, Bl, srow + it * 32, skq, breg[it]);
      }
      __syncthreads();

      const __bf16* PH = diag ? Ah : Bh;
      const __bf16* PL = diag ? Al : Bl;

      bf16x8 fah[4], fal[4];
#pragma unroll
      for (int i = 0; i < 4; i++) {
        int ar = wr * 64 + i * 16 + ln;
        fah[i] = frag_ld(Ah, ar, quad);
        fal[i] = frag_ld(Al, ar, quad);
      }

      if (kc + KB < ksl) {                // prefetch next chunk under MFMA
#pragma unroll
        for (int it = 0; it < 4; it++)
          areg[it] = *(const float4*)(Abase + (size_t)(srow + it * 32) * Sn + (kc + KB) + skq * 4);
        if (!diag) {
#pragma unroll
          for (int it = 0; it < 4; it++)
            breg[it] = *(const float4*)(Bbase + (size_t)(srow + it * 32) * Sn + (kc + KB) + skq * 4);
        }
      }

#pragma unroll
      for (int j = 0; j < 4; j++) {
        int br = wc * 64 + j * 16 + ln;
        bf16x8 fbh = frag_ld(PH, br, quad);
        bf16x8 fbl = frag_ld(PL, br, quad);
#pragma unroll
        for (int i = 0; i < 4; i++) {
          acc[i][j] = __builtin_amdgcn_mfma_f32_16x16x32_bf16(fah[i], fbh, acc[i][j], 0, 0, 0);
          acc[i][j] = __builtin_amdgcn_mfma_f32_16x16x32_bf16(fah[i], fbl, acc[i][j], 0, 0, 0);
          acc[i][j] = __builtin_amdgcn_mfma_f32_16x16x32_bf16(fal[i], fbh, acc[i][j], 0, 0, 0);
        }
      }
      __syncthreads();
    }

    float* E = energy + (size_t)b * Cn * Cn;
#pragma unroll
    for (int i = 0; i < 4; i++)
#pragma unroll
      for (int j = 0; j < 4; j++) {
        int c0 = ti * TILE + wr * 64 + i * 16 + quad * 4;
        int d  = tj * TILE + wc * 64 + j * 16 + ln;
#pragma unroll
        for (int r = 0; r < 4; r++) {
          float v = acc[i][j][r];
          atomicAdd(&E[(size_t)(c0 + r) * Cn + d], v);
          if (!diag) atomicAdd(&E[(size_t)d * Cn + (c0 + r)], v);
        }
      }
  }
  grid_barrier(1);

  // ---- phase 2: softmax(min-trick), wave per row ----
  for (int row = blockIdx.x * 4 + wv; row < Bn * Cn; row += gridDim.x * 4) {
    float4 e = *(const float4*)&energy[(size_t)row * Cn + lane * 4];
    float m = fminf(fminf(e.x, e.y), fminf(e.z, e.w));
#pragma unroll
    for (int off = 32; off > 0; off >>= 1) m = fminf(m, __shfl_xor(m, off));
    float4 p;
    p.x = expf(m - e.x); p.y = expf(m - e.y);
    p.z = expf(m - e.z); p.w = expf(m - e.w);
    float s = p.x + p.y + p.z + p.w;
#pragma unroll
    for (int off = 32; off > 0; off >>= 1) s += __shfl_xor(s, off);
    float inv = 1.f / s;
    p.x *= inv; p.y *= inv; p.z *= inv; p.w *= inv;
    *(float4*)&energy[(size_t)row * Cn + lane * 4] = p;
  }
  grid_barrier(2);

  // ---- phase 3: y = w@v (split-bf16 MFMA), out = alpha*y + x ----
  const float al = alpha[0];
  for (unsigned jj = blockIdx.x; jj < 2048; jj += gridDim.x) {
    const int b  = jj >> 8;
    const int m0 = ((jj >> 7) & 1) * 128;
    const int s0 = (jj & 127) * 128;

    const float* Wb = energy + ((size_t)b * Cn + m0) * Cn;
    const float* Vb = x + (size_t)b * Cn * Sn;

    float4 areg[4];
    float  breg[16];
#pragma unroll
    for (int it = 0; it < 4; it++)
      areg[it] = *(const float4*)(Wb + (size_t)(srow + it * 32) * Cn + skq * 4);
#pragma unroll
    for (int it = 0; it < 4; it++) {
      const float* col = Vb + (size_t)(skq * 4) * Sn + s0 + srow + it * 32;
      breg[it * 4 + 0] = col[0];
      breg[it * 4 + 1] = col[(size_t)Sn];
      breg[it * 4 + 2] = col[(size_t)2 * Sn];
      breg[it * 4 + 3] = col[(size_t)3 * Sn];
    }

    f32x4 acc[4][4];
#pragma unroll
    for (int i = 0; i < 4; i++)
#pragma unroll
      for (int j = 0; j < 4; j++) acc[i][j] = (f32x4){0.f, 0.f, 0.f, 0.f};

    for (int kc = 0; kc < Cn; kc += KB) {
#pragma unroll
      for (int it = 0; it < 4; it++) split_store(Ah, Al, srow + it * 32, skq, areg[it]);
#pragma unroll
      for (int it = 0; it < 4; it++) {
        float4 bv = make_float4(breg[it * 4 + 0], breg[it * 4 + 1],
                                breg[it * 4 + 2], breg[it * 4 + 3]);
        split_store(Bh, Bl, srow + it * 32, skq, bv);
      }
      __syncthreads();

      bf16x8 fah[4], fal[4];
#pragma unroll
      for (int i = 0; i < 4; i++) {
        int ar = wr * 64 + i * 16 + ln;
        fah[i] = frag_ld(Ah, ar, quad);
        fal[i] = frag_ld(Al, ar, quad);
      }

      if (kc + KB < Cn) {
#pragma unroll
        for (int it = 0; it < 4; it++)
          areg[it] = *(const float4*)(Wb + (size_t)(srow + it * 32) * Cn + (kc + KB) + skq * 4);
#pragma unroll
        for (int it = 0; it < 4; it++) {
          const float* col = Vb + (size_t)((kc + KB) + skq * 4) * Sn + s0 + srow + it * 32;
          breg[it * 4 + 0] = col[0];
          breg[it * 4 + 1] = col[(size_t)Sn];
          breg[it * 4 + 2] = col[(size_t)2 * Sn];
          breg[it * 4 + 3] = col[(size_t)3 * Sn];
        }
      }

#pragma unroll
      for (int j = 0; j < 4; j++) {
        int br = wc * 64 + j * 16 + ln;
        bf16x8 fbh = frag_ld(Bh, br, quad);
        bf16x8 fbl = frag_ld(Bl, br, quad);
#pragma unroll
        for (int i = 0; i < 4; i++) {
          acc[i][j] = __builtin_amdgcn_mfma_f32_16x16x32_bf16(fah[i], fbh, acc[i][j], 0, 0, 0);
          acc[i][j] = __builtin_amdgcn_mfma_f32_16x16x32_bf16(fah[i], fbl, acc[i][j], 0, 0, 0);
          acc[i][j] = __builtin_amdgcn_mfma_f32_16x16x32_bf16(fal[i], fbh, acc[i][j], 0, 0, 0);
        }
      }
      __syncthreads();
    }

    const float* xb = x   + (size_t)b * Cn * Sn;
    float*       ob = out + (size_t)b * Cn * Sn;
#pragma unroll
    for (int i = 0; i < 4; i++)
#pragma unroll
      for (int j = 0; j < 4; j++) {
        int c = m0 + wr * 64 + i * 16 + quad * 4;
        int s = s0 + wc * 64 + j * 16 + ln;
        const float* xr = xb + (size_t)c * Sn + s;
        float*       op = ob + (size_t)c * Sn + s;
#pragma unroll
        for (int r = 0; r < 4; r++)
          op[(size_t)r * Sn] = al * acc[i][j][r] + xr[(size_t)r * Sn];
      }
  }
}

// ================= fallback path (R3-verified standalone kernels) ==========
static constexpr int KSPLIT = 16;
static constexpr int KSLICE = Sn / KSPLIT;  // 1024

__global__ __launch_bounds__(256, 2) void gram_kernel(const float* __restrict__ x,
                                                      float* __restrict__ energy) {
  const int b    = blockIdx.z;
  const int tsel = blockIdx.y;
  const int kk   = blockIdx.x;
  const int ti   = (tsel == 1) ? 1 : 0;
  const int tj   = (tsel == 0) ? 0 : 1;
  const bool diag = (tsel < 2);

  const float* vb    = x + (size_t)b * Cn * Sn;
  const float* Abase = vb + (size_t)(ti * TILE) * Sn + kk * KSLICE;
  const float* Bbase = vb + (size_t)(tj * TILE) * Sn + kk * KSLICE;

  __shared__ __align__(16) __bf16 Ah[TILE * 32];
  __shared__ __align__(16) __bf16 Al[TILE * 32];
  __shared__ __align__(16) __bf16 Bh[TILE * 32];
  __shared__ __align__(16) __bf16 Bl[TILE * 32];

  const int t    = threadIdx.x;
  const int lane = t & 63;
  const int wv   = t >> 6;
  const int wr   = wv >> 1;
  const int wc   = wv & 1;
  const int ln   = lane & 15;
  const int quad = lane >> 4;
  const int srow = t >> 3;
  const int skq  = t & 7;

  float4 areg[4], breg[4];
#pragma unroll
  for (int it = 0; it < 4; it++)
    areg[it] = *(const float4*)(Abase + (size_t)(srow + it * 32) * Sn + skq * 4);
  if (!diag) {
#pragma unroll
    for (int it = 0; it < 4; it++)
      breg[it] = *(const float4*)(Bbase + (size_t)(srow + it * 32) * Sn + skq * 4);
  }

  f32x4 acc[4][4];
#pragma unroll
  for (int i = 0; i < 4; i++)
#pragma unroll
    for (int j = 0; j < 4; j++) acc[i][j] = (f32x4){0.f, 0.f, 0.f, 0.f};

  for (int kc = 0; kc < KSLICE; kc += KB) {
#pragma unroll
    for (int it = 0; it < 4; it++) split_store(Ah, Al, srow + it * 32, skq, areg[it]);
    if (!diag) {
#pragma unroll
      for (int it = 0; it < 4; it++) split_store(Bh, Bl, srow + it * 32, skq, breg[it]);
    }
    __syncthreads();

    const __bf16* PH = diag ? Ah : Bh;
    const __bf16* PL = diag ? Al : Bl;

    bf16x8 fah[4], fal[4];
#pragma unroll
    for (int i = 0; i < 4; i++) {
      int ar = wr * 64 + i * 16 + ln;
      fah[i] = frag_ld(Ah, ar, quad);
      fal[i] = frag_ld(Al, ar, quad);
    }

    if (kc + KB < KSLICE) {
#pragma unroll
      for (int it = 0; it < 4; it++)
        areg[it] = *(const float4*)(Abase + (size_t)(srow + it * 32) * Sn + (kc + KB) + skq * 4);
      if (!diag) {
#pragma unroll
        for (int it = 0; it < 4; it++)
          breg[it] = *(const float4*)(Bbase + (size_t)(srow + it * 32) * Sn + (kc + KB) + skq * 4);
      }
    }

#pragma unroll
    for (int j = 0; j < 4; j++) {
      int br = wc * 64 + j * 16 + ln;
      bf16x8 fbh = frag_ld(PH, br, quad);
      bf16x8 fbl = frag_ld(PL, br, quad);
#pragma unroll
      for (int i = 0; i < 4; i++) {
        acc[i][j] = __builtin_amdgcn_mfma_f32_16x16x32_bf16(fah[i], fbh, acc[i][j], 0, 0, 0);
        acc[i][j] = __builtin_amdgcn_mfma_f32_16x16x32_bf16(fah[i], fbl, acc[i][j], 0, 0, 0);
        acc[i][j] = __builtin_amdgcn_mfma_f32_16x16x32_bf16(fal[i], fbh, acc[i][j], 0, 0, 0);
      }
    }
    __syncthreads();
  }

  float* E = energy + (size_t)b * Cn * Cn;
#pragma unroll
  for (int i = 0; i < 4; i++)
#pragma unroll
    for (int j = 0; j < 4; j++) {
      int c0 = ti * TILE + wr * 64 + i * 16 + quad * 4;
      int d  = tj * TILE + wc * 64 + j * 16 + ln;
#pragma unroll
      for (int r = 0; r < 4; r++) {
        float v = acc[i][j][r];
        atomicAdd(&E[(size_t)(c0 + r) * Cn + d], v);
        if (tsel == 2) atomicAdd(&E[(size_t)d * Cn + (c0 + r)], v);
      }
    }
}

__global__ __launch_bounds__(256) void softmax_kernel(float* __restrict__ energy) {
  const int wv   = threadIdx.x >> 6;
  const int lane = threadIdx.x & 63;
  const int row  = blockIdx.x * 4 + wv;

  float4 e = *(const float4*)&energy[(size_t)row * Cn + lane * 4];
  float m = fminf(fminf(e.x, e.y), fminf(e.z, e.w));
#pragma unroll
  for (int off = 32; off > 0; off >>= 1) m = fminf(m, __shfl_xor(m, off));

  float4 p;
  p.x = expf(m - e.x); p.y = expf(m - e.y);
  p.z = expf(m - e.z); p.w = expf(m - e.w);
  float s = p.x + p.y + p.z + p.w;
#pragma unroll
  for (int off = 32; off > 0; off >>= 1) s += __shfl_xor(s, off);

  float inv = 1.f / s;
  p.x *= inv; p.y *= inv; p.z *= inv; p.w *= inv;
  *(float4*)&energy[(size_t)row * Cn + lane * 4] = p;
}

__global__ __launch_bounds__(256, 2) void ygemm_mfma_kernel(const float* __restrict__ w,
                                                            const float* __restrict__ x,
                                                            const float* __restrict__ alpha,
                                                            float* __restrict__ out) {
  const int b  = blockIdx.z;
  const int m0 = blockIdx.y * 128;
  const int s0 = blockIdx.x * 128;

  const float* Wb = w + ((size_t)b * Cn + m0) * Cn;
  const float* Vb = x + (size_t)b * Cn * Sn;

  __shared__ __align__(16) __bf16 Ah[128 * 32];
  __shared__ __align__(16) __bf16 Al[128 * 32];
  __shared__ __align__(16) __bf16 Bh[128 * 32];
  __shared__ __align__(16) __bf16 Bl[128 * 32];

  const int t    = threadIdx.x;
  const int lane = t & 63;
  const int wv   = t >> 6;
  const int wr   = wv >> 1;
  const int wc   = wv & 1;
  const int ln   = lane & 15;
  const int quad = lane >> 4;
  const int srow = t >> 3;
  const int skq  = t & 7;

  float4 areg[4];
  float  breg[16];

#pragma unroll
  for (int it = 0; it < 4; it++)
    areg[it] = *(const float4*)(Wb + (size_t)(srow + it * 32) * Cn + skq * 4);
#pragma unroll
  for (int it = 0; it < 4; it++) {
    const float* col = Vb + (size_t)(skq * 4) * Sn + s0 + srow + it * 32;
    breg[it * 4 + 0] = col[0];
    breg[it * 4 + 1] = col[(size_t)Sn];
    breg[it * 4 + 2] = col[(size_t)2 * Sn];
    breg[it * 4 + 3] = col[(size_t)3 * Sn];
  }

  f32x4 acc[4][4];
#pragma unroll
  for (int i = 0; i < 4; i++)
#pragma unroll
    for (int j = 0; j < 4; j++) acc[i][j] = (f32x4){0.f, 0.f, 0.f, 0.f};

  for (int kc = 0; kc < Cn; kc += KB) {
#pragma unroll
    for (int it = 0; it < 4; it++) split_store(Ah, Al, srow + it * 32, skq, areg[it]);
#pragma unroll
    for (int it = 0; it < 4; it++) {
      float4 bv = make_float4(breg[it * 4 + 0], breg[it * 4 + 1],
                              breg[it * 4 + 2], breg[it * 4 + 3]);
      split_store(Bh, Bl, srow + it * 32, skq, bv);
    }
    __syncthreads();

    bf16x8 fah[4], fal[4];
#pragma unroll
    for (int i = 0; i < 4; i++) {
      int ar = wr * 64 + i * 16 + ln;
      fah[i] = frag_ld(Ah, ar, quad);
      fal[i] = frag_ld(Al, ar, quad);
    }

    if (kc + KB < Cn) {
#pragma unroll
      for (int it = 0; it < 4; it++)
        areg[it] = *(const float4*)(Wb + (size_t)(srow + it * 32) * Cn + (kc + KB) + skq * 4);
#pragma unroll
      for (int it = 0; it < 4; it++) {
        const float* col = Vb + (size_t)((kc + KB) + skq * 4) * Sn + s0 + srow + it * 32;
        breg[it * 4 + 0] = col[0];
        breg[it * 4 + 1] = col[(size_t)Sn];
        breg[it * 4 + 2] = col[(size_t)2 * Sn];
        breg[it * 4 + 3] = col[(size_t)3 * Sn];
      }
    }

#pragma unroll
    for (int j = 0; j < 4; j++) {
      int br = wc * 64 + j * 16 + ln;
      bf16x8 fbh = frag_ld(Bh, br, quad);
      bf16x8 fbl = frag_ld(Bl, br, quad);
#pragma unroll
      for (int i = 0; i < 4; i++) {
        acc[i][j] = __builtin_amdgcn_mfma_f32_16x16x32_bf16(fah[i], fbh, acc[i][j], 0, 0, 0);
        acc[i][j] = __builtin_amdgcn_mfma_f32_16x16x32_bf16(fah[i], fbl, acc[i][j], 0, 0, 0);
        acc[i][j] = __builtin_amdgcn_mfma_f32_16x16x32_bf16(fal[i], fbh, acc[i][j], 0, 0, 0);
      }
    }
    __syncthreads();
  }

  const float al = alpha[0];
#pragma unroll
  for (int i = 0; i < 4; i++)
#pragma unroll
    for (int j = 0; j < 4; j++) {
      int c = m0 + wr * 64 + i * 16 + quad * 4;
      int s = s0 + wc * 64 + j * 16 + ln;
      const float* xr = x   + ((size_t)b * Cn + c) * Sn + s;
      float*       op = out + ((size_t)b * Cn + c) * Sn + s;
#pragma unroll
      for (int r = 0; r < 4; r++)
        op[(size_t)r * Sn] = al * acc[i][j][r] + xr[(size_t)r * Sn];
    }
}

extern "C" void kernel_launch(void* const* d_in, const int* in_sizes, int n_in,
                              void* d_out, int out_size, void* d_ws, size_t ws_size,
                              hipStream_t stream) {
  const float* x     = (const float*)d_in[0];
  const float* alpha = (const float*)d_in[1];
  float*       out   = (float*)d_out;
  float*       energy = (float*)d_ws;          // B*C*C fp32 = 2 MB; becomes w in-place

  // One-time: co-resident capacity for the persistent fused kernel.
  static int g_grid = -2;
  if (g_grid == -2) {
    int nb = 0, cu = 0;
    hipDeviceProp_t prop;
    if (hipGetDeviceProperties(&prop, 0) == hipSuccess) cu = prop.multiProcessorCount;
    if (cu > 0 &&
        hipOccupancyMaxActiveBlocksPerMultiprocessor(&nb, fused_kernel, 256, 0) == hipSuccess &&
        nb >= 1) {
      long g = (long)nb * cu;
      g_grid = (int)(g > 512 ? 512 : g);
    } else {
      g_grid = 0;                              // fallback marker
    }
  }

  if (g_grid >= 64) {
    fused_kernel<<<dim3(g_grid), dim3(256), 0, stream>>>(x, alpha, out, energy);
  } else {
    const size_t energy_bytes = (size_t)Bn * Cn * Cn * sizeof(float);
    hipMemsetAsync(energy, 0, energy_bytes, stream);
    dim3 g1(KSPLIT, 3, Bn);
    gram_kernel<<<g1, 256, 0, stream>>>(x, energy);
    softmax_kernel<<<(Bn * Cn) / 4, 256, 0, stream>>>(energy);
    dim3 g3(Sn / 128, Cn / 128, Bn);
    ygemm_mfma_kernel<<<g3, 256, 0, stream>>>(energy, x, alpha, out);
  }
}

// Round 5
// 459.912 us; speedup vs baseline: 1.1825x; 1.1825x over previous
//
#include <hip/hip_runtime.h>
#include <math.h>

static constexpr int Bn = 8;
static constexpr int Cn = 256;
static constexpr int Sn = 16384;   // 128*128

typedef __bf16 bf16x4 __attribute__((ext_vector_type(4)));
typedef __bf16 bf16x8 __attribute__((ext_vector_type(8)));
typedef float  f32x4  __attribute__((ext_vector_type(4)));

static constexpr int TILE = 128;
static constexpr int KB   = 32;

// ---------------- shared LDS layout helpers ----------------
// Tile buffer: 128 rows x 32 bf16 (one K-chunk), zero pad, XOR chunk swizzle.
// Row = 64 B = 4 chunks of 16 B. Data chunk c of row r lives at slot c^(r&3).
// -> frag reads (b128) 8 accesses/bank (floor), staging writes (b64) 4/bank.
__device__ __forceinline__ void split_store(__bf16* __restrict__ Hi, __bf16* __restrict__ Lo,
                                            int row, int kq, float4 v) {
  __bf16 h0 = (__bf16)v.x, h1 = (__bf16)v.y, h2 = (__bf16)v.z, h3 = (__bf16)v.w;
  int off = row * 32 + (((kq >> 1) ^ (row & 3)) << 3) + ((kq & 1) << 2);
  *(bf16x4*)&Hi[off] = (bf16x4){h0, h1, h2, h3};
  *(bf16x4*)&Lo[off] = (bf16x4){(__bf16)(v.x - (float)h0), (__bf16)(v.y - (float)h1),
                                (__bf16)(v.z - (float)h2), (__bf16)(v.w - (float)h3)};
}

__device__ __forceinline__ bf16x8 frag_ld(const __bf16* __restrict__ P, int row, int quad) {
  return *(const bf16x8*)&P[row * 32 + ((quad ^ (row & 3)) << 3)];
}

// ---------------- Kernel 1: partial Gram (energy) via split-bf16 MFMA -------
// energy[b][c][d] = sum_s v[b,c,s] * v[b,d,s]; symmetric.
// 1024 fine-grained jobs (2 blocks/CU co-resident, HW backfill balances):
//   job <  512: diagonal tiles, ksl=512 (8b x 2tiles x 32 kslices, 16 chunks)
//   job >= 512: off-diag (0,1),  ksl=256 (8b x 64 kslices, 8 chunks) + mirror
// Double-buffered LDS: one barrier per chunk; staging of chunk k+1 and global
// loads of chunk k+2 overlap the MFMA cluster of chunk k.
__global__ __launch_bounds__(256, 2) void gram_kernel(const float* __restrict__ x,
                                                      float* __restrict__ energy) {
  const int job  = blockIdx.x;            // 0..1023
  const bool diag = (job < 512);
  int b, ti, tj, kk, ksl;
  if (diag) {
    b = job >> 6; int r = job & 63;
    ti = tj = r >> 5; kk = r & 31; ksl = 512;
  } else {
    int j2 = job - 512;
    b = j2 >> 6; kk = j2 & 63; ti = 0; tj = 1; ksl = 256;
  }

  const float* vb    = x + (size_t)b * Cn * Sn;
  const float* Abase = vb + (size_t)(ti * TILE) * Sn + (size_t)kk * ksl;
  const float* Bbase = vb + (size_t)(tj * TILE) * Sn + (size_t)kk * ksl;

  __shared__ __align__(16) __bf16 Ah[2][TILE * 32];
  __shared__ __align__(16) __bf16 Al[2][TILE * 32];
  __shared__ __align__(16) __bf16 Bh[2][TILE * 32];
  __shared__ __align__(16) __bf16 Bl[2][TILE * 32];

  const int t    = threadIdx.x;           // 0..255
  const int lane = t & 63;
  const int wv   = t >> 6;
  const int wr   = wv >> 1;               // wave row (c)
  const int wc   = wv & 1;                // wave col (d)
  const int ln   = lane & 15;
  const int quad = lane >> 4;
  const int srow = t >> 3;                // staging row base 0..31
  const int skq  = t & 7;                 // float4 index within chunk

  float4 areg[4], breg[4];

  // prologue: stage chunk 0, load chunk 1 into regs
#pragma unroll
  for (int it = 0; it < 4; it++)
    areg[it] = *(const float4*)(Abase + (size_t)(srow + it * 32) * Sn + skq * 4);
  if (!diag) {
#pragma unroll
    for (int it = 0; it < 4; it++)
      breg[it] = *(const float4*)(Bbase + (size_t)(srow + it * 32) * Sn + skq * 4);
  }
#pragma unroll
  for (int it = 0; it < 4; it++) split_store(Ah[0], Al[0], srow + it * 32, skq, areg[it]);
  if (!diag) {
#pragma unroll
    for (int it = 0; it < 4; it++) split_store(Bh[0], Bl[0], srow + it * 32, skq, breg[it]);
  }
#pragma unroll
  for (int it = 0; it < 4; it++)
    areg[it] = *(const float4*)(Abase + (size_t)(srow + it * 32) * Sn + KB + skq * 4);
  if (!diag) {
#pragma unroll
    for (int it = 0; it < 4; it++)
      breg[it] = *(const float4*)(Bbase + (size_t)(srow + it * 32) * Sn + KB + skq * 4);
  }
  __syncthreads();

  f32x4 acc[4][4];
#pragma unroll
  for (int i = 0; i < 4; i++)
#pragma unroll
    for (int j = 0; j < 4; j++) acc[i][j] = (f32x4){0.f, 0.f, 0.f, 0.f};

  int p = 0;
  for (int kc = 0; kc < ksl; kc += KB, p ^= 1) {
    const __bf16* pAh = Ah[p];
    const __bf16* pAl = Al[p];
    const __bf16* pBh = diag ? Ah[p] : Bh[p];
    const __bf16* pBl = diag ? Al[p] : Bl[p];

    bf16x8 fah[4], fal[4];
#pragma unroll
    for (int i = 0; i < 4; i++) {
      int ar = wr * 64 + i * 16 + ln;
      fah[i] = frag_ld(pAh, ar, quad);
      fal[i] = frag_ld(pAl, ar, quad);
    }

    // stage chunk kc+KB from regs into the other buffer (overlaps MFMA)
    if (kc + KB < ksl) {
#pragma unroll
      for (int it = 0; it < 4; it++) split_store(Ah[p ^ 1], Al[p ^ 1], srow + it * 32, skq, areg[it]);
      if (!diag) {
#pragma unroll
        for (int it = 0; it < 4; it++) split_store(Bh[p ^ 1], Bl[p ^ 1], srow + it * 32, skq, breg[it]);
      }
    }
    // issue global loads for chunk kc+2*KB
    if (kc + 2 * KB < ksl) {
#pragma unroll
      for (int it = 0; it < 4; it++)
        areg[it] = *(const float4*)(Abase + (size_t)(srow + it * 32) * Sn + (kc + 2 * KB) + skq * 4);
      if (!diag) {
#pragma unroll
        for (int it = 0; it < 4; it++)
          breg[it] = *(const float4*)(Bbase + (size_t)(srow + it * 32) * Sn + (kc + 2 * KB) + skq * 4);
      }
    }

#pragma unroll
    for (int j = 0; j < 4; j++) {
      int br = wc * 64 + j * 16 + ln;
      bf16x8 fbh = frag_ld(pBh, br, quad);
      bf16x8 fbl = frag_ld(pBl, br, quad);
#pragma unroll
      for (int i = 0; i < 4; i++) {
        acc[i][j] = __builtin_amdgcn_mfma_f32_16x16x32_bf16(fah[i], fbh, acc[i][j], 0, 0, 0);
        acc[i][j] = __builtin_amdgcn_mfma_f32_16x16x32_bf16(fah[i], fbl, acc[i][j], 0, 0, 0);
        acc[i][j] = __builtin_amdgcn_mfma_f32_16x16x32_bf16(fal[i], fbh, acc[i][j], 0, 0, 0);
      }
    }
    __syncthreads();     // single barrier per chunk (double-buffered)
  }

  // epilogue: C/D layout col=lane&15, row=quad*4+reg; mirror for off-diag tile
  float* E = energy + (size_t)b * Cn * Cn;
#pragma unroll
  for (int i = 0; i < 4; i++)
#pragma unroll
    for (int j = 0; j < 4; j++) {
      int c0 = ti * TILE + wr * 64 + i * 16 + quad * 4;
      int d  = tj * TILE + wc * 64 + j * 16 + ln;
#pragma unroll
      for (int r = 0; r < 4; r++) {
        float v = acc[i][j][r];
        atomicAdd(&E[(size_t)(c0 + r) * Cn + d], v);
        if (!diag) atomicAdd(&E[(size_t)d * Cn + (c0 + r)], v);
      }
    }
}

// ---------------- Kernel 2: softmax, wave per row, no barriers ----------------
// softmax(max_d(e) - e) over d  ==  exp(e_min - e_d) / sum  (row max cancels)
__global__ __launch_bounds__(256) void softmax_kernel(float* __restrict__ energy) {
  const int wv   = threadIdx.x >> 6;
  const int lane = threadIdx.x & 63;
  const int row  = blockIdx.x * 4 + wv;

  float4 e = *(const float4*)&energy[(size_t)row * Cn + lane * 4];
  float m = fminf(fminf(e.x, e.y), fminf(e.z, e.w));
#pragma unroll
  for (int off = 32; off > 0; off >>= 1) m = fminf(m, __shfl_xor(m, off));

  float4 p;
  p.x = expf(m - e.x); p.y = expf(m - e.y);
  p.z = expf(m - e.z); p.w = expf(m - e.w);
  float s = p.x + p.y + p.z + p.w;
#pragma unroll
  for (int off = 32; off > 0; off >>= 1) s += __shfl_xor(s, off);

  float inv = 1.f / s;
  p.x *= inv; p.y *= inv; p.z *= inv; p.w *= inv;
  *(float4*)&energy[(size_t)row * Cn + lane * 4] = p;
}

// ---------------- Kernel 3: y = w @ v via split-bf16 MFMA, out = alpha*y + x -
// A = w[b] (256x256 fp32, k contiguous). B = v[b] (k slow axis -> transpose via
// per-lane k-column scalar loads). Double-buffered LDS, one barrier per chunk.
__global__ __launch_bounds__(256, 2) void ygemm_mfma_kernel(const float* __restrict__ w,
                                                            const float* __restrict__ x,
                                                            const float* __restrict__ alpha,
                                                            float* __restrict__ out) {
  const int b  = blockIdx.z;
  const int m0 = blockIdx.y * 128;        // output row tile (c)
  const int s0 = blockIdx.x * 128;        // output col tile (s)

  const float* Wb = w + ((size_t)b * Cn + m0) * Cn;
  const float* Vb = x + (size_t)b * Cn * Sn;

  __shared__ __align__(16) __bf16 Ah[2][128 * 32];
  __shared__ __align__(16) __bf16 Al[2][128 * 32];
  __shared__ __align__(16) __bf16 Bh[2][128 * 32];   // transposed: [s][k]
  __shared__ __align__(16) __bf16 Bl[2][128 * 32];

  const int t    = threadIdx.x;
  const int lane = t & 63;
  const int wv   = t >> 6;
  const int wr   = wv >> 1;               // wave row (m)
  const int wc   = wv & 1;                // wave col (s)
  const int ln   = lane & 15;
  const int quad = lane >> 4;
  const int srow = t >> 3;                // staging row base 0..31
  const int skq  = t & 7;                 // chunk-quad (k group of 4)

  float4 areg[4];
  float  breg[16];

  // prologue: stage chunk 0, load chunk 1
#pragma unroll
  for (int it = 0; it < 4; it++)
    areg[it] = *(const float4*)(Wb + (size_t)(srow + it * 32) * Cn + skq * 4);
#pragma unroll
  for (int it = 0; it < 4; it++) {
    const float* col = Vb + (size_t)(skq * 4) * Sn + s0 + srow + it * 32;
    breg[it * 4 + 0] = col[0];
    breg[it * 4 + 1] = col[(size_t)Sn];
    breg[it * 4 + 2] = col[(size_t)2 * Sn];
    breg[it * 4 + 3] = col[(size_t)3 * Sn];
  }
#pragma unroll
  for (int it = 0; it < 4; it++) split_store(Ah[0], Al[0], srow + it * 32, skq, areg[it]);
#pragma unroll
  for (int it = 0; it < 4; it++) {
    float4 bv = make_float4(breg[it * 4 + 0], breg[it * 4 + 1],
                            breg[it * 4 + 2], breg[it * 4 + 3]);
    split_store(Bh[0], Bl[0], srow + it * 32, skq, bv);
  }
#pragma unroll
  for (int it = 0; it < 4; it++)
    areg[it] = *(const float4*)(Wb + (size_t)(srow + it * 32) * Cn + KB + skq * 4);
#pragma unroll
  for (int it = 0; it < 4; it++) {
    const float* col = Vb + (size_t)(KB + skq * 4) * Sn + s0 + srow + it * 32;
    breg[it * 4 + 0] = col[0];
    breg[it * 4 + 1] = col[(size_t)Sn];
    breg[it * 4 + 2] = col[(size_t)2 * Sn];
    breg[it * 4 + 3] = col[(size_t)3 * Sn];
  }
  __syncthreads();

  f32x4 acc[4][4];
#pragma unroll
  for (int i = 0; i < 4; i++)
#pragma unroll
    for (int j = 0; j < 4; j++) acc[i][j] = (f32x4){0.f, 0.f, 0.f, 0.f};

  int p = 0;
  for (int kc = 0; kc < Cn; kc += KB, p ^= 1) {
    bf16x8 fah[4], fal[4];
#pragma unroll
    for (int i = 0; i < 4; i++) {
      int ar = wr * 64 + i * 16 + ln;
      fah[i] = frag_ld(Ah[p], ar, quad);
      fal[i] = frag_ld(Al[p], ar, quad);
    }

    if (kc + KB < Cn) {
#pragma unroll
      for (int it = 0; it < 4; it++) split_store(Ah[p ^ 1], Al[p ^ 1], srow + it * 32, skq, areg[it]);
#pragma unroll
      for (int it = 0; it < 4; it++) {
        float4 bv = make_float4(breg[it * 4 + 0], breg[it * 4 + 1],
                                breg[it * 4 + 2], breg[it * 4 + 3]);
        split_store(Bh[p ^ 1], Bl[p ^ 1], srow + it * 32, skq, bv);
      }
    }
    if (kc + 2 * KB < Cn) {
#pragma unroll
      for (int it = 0; it < 4; it++)
        areg[it] = *(const float4*)(Wb + (size_t)(srow + it * 32) * Cn + (kc + 2 * KB) + skq * 4);
#pragma unroll
      for (int it = 0; it < 4; it++) {
        const float* col = Vb + (size_t)((kc + 2 * KB) + skq * 4) * Sn + s0 + srow + it * 32;
        breg[it * 4 + 0] = col[0];
        breg[it * 4 + 1] = col[(size_t)Sn];
        breg[it * 4 + 2] = col[(size_t)2 * Sn];
        breg[it * 4 + 3] = col[(size_t)3 * Sn];
      }
    }

#pragma unroll
    for (int j = 0; j < 4; j++) {
      int br = wc * 64 + j * 16 + ln;
      bf16x8 fbh = frag_ld(Bh[p], br, quad);
      bf16x8 fbl = frag_ld(Bl[p], br, quad);
#pragma unroll
      for (int i = 0; i < 4; i++) {
        acc[i][j] = __builtin_amdgcn_mfma_f32_16x16x32_bf16(fah[i], fbh, acc[i][j], 0, 0, 0);
        acc[i][j] = __builtin_amdgcn_mfma_f32_16x16x32_bf16(fah[i], fbl, acc[i][j], 0, 0, 0);
        acc[i][j] = __builtin_amdgcn_mfma_f32_16x16x32_bf16(fal[i], fbh, acc[i][j], 0, 0, 0);
      }
    }
    __syncthreads();     // single barrier per chunk
  }

  // epilogue: fuse residual + alpha
  const float al = alpha[0];
#pragma unroll
  for (int i = 0; i < 4; i++)
#pragma unroll
    for (int j = 0; j < 4; j++) {
      int c = m0 + wr * 64 + i * 16 + quad * 4;
      int s = s0 + wc * 64 + j * 16 + ln;
      const float* xr = x   + ((size_t)b * Cn + c) * Sn + s;
      float*       op = out + ((size_t)b * Cn + c) * Sn + s;
#pragma unroll
      for (int r = 0; r < 4; r++)
        op[(size_t)r * Sn] = al * acc[i][j][r] + xr[(size_t)r * Sn];
    }
}

extern "C" void kernel_launch(void* const* d_in, const int* in_sizes, int n_in,
                              void* d_out, int out_size, void* d_ws, size_t ws_size,
                              hipStream_t stream) {
  const float* x     = (const float*)d_in[0];
  const float* alpha = (const float*)d_in[1];
  float*       out   = (float*)d_out;
  float*       energy = (float*)d_ws;          // B*C*C fp32 = 2 MB; becomes w in-place

  const size_t energy_bytes = (size_t)Bn * Cn * Cn * sizeof(float);
  hipMemsetAsync(energy, 0, energy_bytes, stream);

  gram_kernel<<<dim3(1024), 256, 0, stream>>>(x, energy);

  softmax_kernel<<<(Bn * Cn) / 4, 256, 0, stream>>>(energy);

  dim3 g3(Sn / 128, Cn / 128, Bn);             // 128 x 2 x 8 = 2048 blocks
  ygemm_mfma_kernel<<<g3, 256, 0, stream>>>(energy, x, alpha, out);
}

// Round 6
// 331.980 us; speedup vs baseline: 1.6381x; 1.3854x over previous
//
#include <hip/hip_runtime.h>
#include <math.h>

static constexpr int Bn = 8;
static constexpr int Cn = 256;
static constexpr int Sn = 16384;   // 128*128

typedef __bf16 bf16x4 __attribute__((ext_vector_type(4)));
typedef __bf16 bf16x8 __attribute__((ext_vector_type(8)));
typedef float  f32x4  __attribute__((ext_vector_type(4)));

static constexpr int TILE   = 128;
static constexpr int KB     = 32;
static constexpr int KSPLIT = 16;
static constexpr int KSLICE = Sn / KSPLIT;  // 1024

// ---------------- shared LDS layout helpers ----------------
// Tile buffer: 128 rows x 32 bf16 (one K-chunk), zero pad, XOR chunk swizzle.
// Row = 64 B = 4 chunks of 16 B. Data chunk c of row r lives at slot c^(r&3).
__device__ __forceinline__ void split_store(__bf16* __restrict__ Hi, __bf16* __restrict__ Lo,
                                            int row, int kq, float4 v) {
  __bf16 h0 = (__bf16)v.x, h1 = (__bf16)v.y, h2 = (__bf16)v.z, h3 = (__bf16)v.w;
  int off = row * 32 + (((kq >> 1) ^ (row & 3)) << 3) + ((kq & 1) << 2);
  *(bf16x4*)&Hi[off] = (bf16x4){h0, h1, h2, h3};
  *(bf16x4*)&Lo[off] = (bf16x4){(__bf16)(v.x - (float)h0), (__bf16)(v.y - (float)h1),
                                (__bf16)(v.z - (float)h2), (__bf16)(v.w - (float)h3)};
}

__device__ __forceinline__ bf16x8 frag_ld(const __bf16* __restrict__ P, int row, int quad) {
  return *(const bf16x8*)&P[row * 32 + ((quad ^ (row & 3)) << 3)];
}

// ---------------- Kernel 1: Gram partials, NO atomics ----------------
// energy[b][c][d] = sum_s v[b,c,s] v[b,d,s]; symmetric -> 3 tiles (2 diag +
// off-diag with mirrored store). Each block writes its k-slice partial to a
// private slot P[kk][b][.][.] with plain coalesced stores; softmax reduces.
// Inner loop identical to the R3-verified gram (single buffer, reg prefetch).
__global__ __launch_bounds__(256, 2) void gram_part_kernel(const float* __restrict__ x,
                                                           float* __restrict__ P) {
  const int b    = blockIdx.z;
  const int tsel = blockIdx.y;            // 0,1 diag; 2 off-diag
  const int kk   = blockIdx.x;            // 0..15
  const int ti   = (tsel == 1) ? 1 : 0;
  const int tj   = (tsel == 0) ? 0 : 1;
  const bool diag = (tsel < 2);

  const float* vb    = x + (size_t)b * Cn * Sn;
  const float* Abase = vb + (size_t)(ti * TILE) * Sn + kk * KSLICE;
  const float* Bbase = vb + (size_t)(tj * TILE) * Sn + kk * KSLICE;

  __shared__ __align__(16) __bf16 Ah[TILE * 32];
  __shared__ __align__(16) __bf16 Al[TILE * 32];
  __shared__ __align__(16) __bf16 Bh[TILE * 32];
  __shared__ __align__(16) __bf16 Bl[TILE * 32];

  const int t    = threadIdx.x;
  const int lane = t & 63;
  const int wv   = t >> 6;
  const int wr   = wv >> 1;
  const int wc   = wv & 1;
  const int ln   = lane & 15;
  const int quad = lane >> 4;
  const int srow = t >> 3;
  const int skq  = t & 7;

  float4 areg[4], breg[4];
#pragma unroll
  for (int it = 0; it < 4; it++)
    areg[it] = *(const float4*)(Abase + (size_t)(srow + it * 32) * Sn + skq * 4);
  if (!diag) {
#pragma unroll
    for (int it = 0; it < 4; it++)
      breg[it] = *(const float4*)(Bbase + (size_t)(srow + it * 32) * Sn + skq * 4);
  }

  f32x4 acc[4][4];
#pragma unroll
  for (int i = 0; i < 4; i++)
#pragma unroll
    for (int j = 0; j < 4; j++) acc[i][j] = (f32x4){0.f, 0.f, 0.f, 0.f};

  for (int kc = 0; kc < KSLICE; kc += KB) {
#pragma unroll
    for (int it = 0; it < 4; it++) split_store(Ah, Al, srow + it * 32, skq, areg[it]);
    if (!diag) {
#pragma unroll
      for (int it = 0; it < 4; it++) split_store(Bh, Bl, srow + it * 32, skq, breg[it]);
    }
    __syncthreads();

    const __bf16* PH = diag ? Ah : Bh;
    const __bf16* PL = diag ? Al : Bl;

    bf16x8 fah[4], fal[4];
#pragma unroll
    for (int i = 0; i < 4; i++) {
      int ar = wr * 64 + i * 16 + ln;
      fah[i] = frag_ld(Ah, ar, quad);
      fal[i] = frag_ld(Al, ar, quad);
    }

    if (kc + KB < KSLICE) {                // prefetch next chunk under MFMA
#pragma unroll
      for (int it = 0; it < 4; it++)
        areg[it] = *(const float4*)(Abase + (size_t)(srow + it * 32) * Sn + (kc + KB) + skq * 4);
      if (!diag) {
#pragma unroll
        for (int it = 0; it < 4; it++)
          breg[it] = *(const float4*)(Bbase + (size_t)(srow + it * 32) * Sn + (kc + KB) + skq * 4);
      }
    }

#pragma unroll
    for (int j = 0; j < 4; j++) {
      int br = wc * 64 + j * 16 + ln;
      bf16x8 fbh = frag_ld(PH, br, quad);
      bf16x8 fbl = frag_ld(PL, br, quad);
#pragma unroll
      for (int i = 0; i < 4; i++) {
        acc[i][j] = __builtin_amdgcn_mfma_f32_16x16x32_bf16(fah[i], fbh, acc[i][j], 0, 0, 0);
        acc[i][j] = __builtin_amdgcn_mfma_f32_16x16x32_bf16(fah[i], fbl, acc[i][j], 0, 0, 0);
        acc[i][j] = __builtin_amdgcn_mfma_f32_16x16x32_bf16(fal[i], fbh, acc[i][j], 0, 0, 0);
      }
    }
    __syncthreads();
  }

  // epilogue: plain stores to private slot (no atomics, no memset needed).
  // C/D layout col=lane&15, row=quad*4+reg (m89-verified).
  float* Pb = P + ((size_t)kk * Bn + b) * (Cn * Cn);
#pragma unroll
  for (int i = 0; i < 4; i++)
#pragma unroll
    for (int j = 0; j < 4; j++) {
      int c0 = ti * TILE + wr * 64 + i * 16 + quad * 4;
      int d  = tj * TILE + wc * 64 + j * 16 + ln;
#pragma unroll
      for (int r = 0; r < 4; r++) {
        float v = acc[i][j][r];
        Pb[(size_t)(c0 + r) * Cn + d] = v;
        if (!diag) Pb[(size_t)d * Cn + (c0 + r)] = v;   // mirror (1,0) tile
      }
    }
}

// ---------------- Kernel 2: reduce partials + softmax, wave per row ----------
// energy = sum_kk P[kk]; softmax(max-e) == exp(e_min - e)/sum (row max cancels)
__global__ __launch_bounds__(256) void softmax_reduce_kernel(const float* __restrict__ P,
                                                             float* __restrict__ w) {
  const int wv   = threadIdx.x >> 6;
  const int lane = threadIdx.x & 63;
  const int row  = blockIdx.x * 4 + wv;     // b*Cn + c
  const size_t off = (size_t)row * Cn + lane * 4;

  float4 e = (float4){0.f, 0.f, 0.f, 0.f};
#pragma unroll
  for (int kk = 0; kk < KSPLIT; kk++) {
    float4 p = *(const float4*)&P[(size_t)kk * (Bn * Cn * Cn) + off];
    e.x += p.x; e.y += p.y; e.z += p.z; e.w += p.w;
  }

  float m = fminf(fminf(e.x, e.y), fminf(e.z, e.w));
#pragma unroll
  for (int o = 32; o > 0; o >>= 1) m = fminf(m, __shfl_xor(m, o));

  float4 p;
  p.x = expf(m - e.x); p.y = expf(m - e.y);
  p.z = expf(m - e.z); p.w = expf(m - e.w);
  float s = p.x + p.y + p.z + p.w;
#pragma unroll
  for (int o = 32; o > 0; o >>= 1) s += __shfl_xor(s, o);

  float inv = 1.f / s;
  p.x *= inv; p.y *= inv; p.z *= inv; p.w *= inv;
  *(float4*)&w[off] = p;
}

// ---------------- Kernel 3: y = w @ v via split-bf16 MFMA, out = alpha*y + x -
// R3-verified version (single buffer, reg prefetch, XOR swizzle).
__global__ __launch_bounds__(256, 2) void ygemm_mfma_kernel(const float* __restrict__ w,
                                                            const float* __restrict__ x,
                                                            const float* __restrict__ alpha,
                                                            float* __restrict__ out) {
  const int b  = blockIdx.z;
  const int m0 = blockIdx.y * 128;
  const int s0 = blockIdx.x * 128;

  const float* Wb = w + ((size_t)b * Cn + m0) * Cn;
  const float* Vb = x + (size_t)b * Cn * Sn;

  __shared__ __align__(16) __bf16 Ah[128 * 32];
  __shared__ __align__(16) __bf16 Al[128 * 32];
  __shared__ __align__(16) __bf16 Bh[128 * 32];   // transposed: [s][k]
  __shared__ __align__(16) __bf16 Bl[128 * 32];

  const int t    = threadIdx.x;
  const int lane = t & 63;
  const int wv   = t >> 6;
  const int wr   = wv >> 1;
  const int wc   = wv & 1;
  const int ln   = lane & 15;
  const int quad = lane >> 4;
  const int srow = t >> 3;
  const int skq  = t & 7;

  float4 areg[4];
  float  breg[16];

#pragma unroll
  for (int it = 0; it < 4; it++)
    areg[it] = *(const float4*)(Wb + (size_t)(srow + it * 32) * Cn + skq * 4);
#pragma unroll
  for (int it = 0; it < 4; it++) {
    const float* col = Vb + (size_t)(skq * 4) * Sn + s0 + srow + it * 32;
    breg[it * 4 + 0] = col[0];
    breg[it * 4 + 1] = col[(size_t)Sn];
    breg[it * 4 + 2] = col[(size_t)2 * Sn];
    breg[it * 4 + 3] = col[(size_t)3 * Sn];
  }

  f32x4 acc[4][4];
#pragma unroll
  for (int i = 0; i < 4; i++)
#pragma unroll
    for (int j = 0; j < 4; j++) acc[i][j] = (f32x4){0.f, 0.f, 0.f, 0.f};

  for (int kc = 0; kc < Cn; kc += KB) {
#pragma unroll
    for (int it = 0; it < 4; it++) split_store(Ah, Al, srow + it * 32, skq, areg[it]);
#pragma unroll
    for (int it = 0; it < 4; it++) {
      float4 bv = make_float4(breg[it * 4 + 0], breg[it * 4 + 1],
                              breg[it * 4 + 2], breg[it * 4 + 3]);
      split_store(Bh, Bl, srow + it * 32, skq, bv);
    }
    __syncthreads();

    bf16x8 fah[4], fal[4];
#pragma unroll
    for (int i = 0; i < 4; i++) {
      int ar = wr * 64 + i * 16 + ln;
      fah[i] = frag_ld(Ah, ar, quad);
      fal[i] = frag_ld(Al, ar, quad);
    }

    if (kc + KB < Cn) {
#pragma unroll
      for (int it = 0; it < 4; it++)
        areg[it] = *(const float4*)(Wb + (size_t)(srow + it * 32) * Cn + (kc + KB) + skq * 4);
#pragma unroll
      for (int it = 0; it < 4; it++) {
        const float* col = Vb + (size_t)((kc + KB) + skq * 4) * Sn + s0 + srow + it * 32;
        breg[it * 4 + 0] = col[0];
        breg[it * 4 + 1] = col[(size_t)Sn];
        breg[it * 4 + 2] = col[(size_t)2 * Sn];
        breg[it * 4 + 3] = col[(size_t)3 * Sn];
      }
    }

#pragma unroll
    for (int j = 0; j < 4; j++) {
      int br = wc * 64 + j * 16 + ln;
      bf16x8 fbh = frag_ld(Bh, br, quad);
      bf16x8 fbl = frag_ld(Bl, br, quad);
#pragma unroll
      for (int i = 0; i < 4; i++) {
        acc[i][j] = __builtin_amdgcn_mfma_f32_16x16x32_bf16(fah[i], fbh, acc[i][j], 0, 0, 0);
        acc[i][j] = __builtin_amdgcn_mfma_f32_16x16x32_bf16(fah[i], fbl, acc[i][j], 0, 0, 0);
        acc[i][j] = __builtin_amdgcn_mfma_f32_16x16x32_bf16(fal[i], fbh, acc[i][j], 0, 0, 0);
      }
    }
    __syncthreads();
  }

  const float al = alpha[0];
#pragma unroll
  for (int i = 0; i < 4; i++)
#pragma unroll
    for (int j = 0; j < 4; j++) {
      int c = m0 + wr * 64 + i * 16 + quad * 4;
      int s = s0 + wc * 64 + j * 16 + ln;
      const float* xr = x   + ((size_t)b * Cn + c) * Sn + s;
      float*       op = out + ((size_t)b * Cn + c) * Sn + s;
#pragma unroll
      for (int r = 0; r < 4; r++)
        op[(size_t)r * Sn] = al * acc[i][j][r] + xr[(size_t)r * Sn];
    }
}

// ============ fallback (R3-measured atomic path, used if ws too small) ======
__global__ __launch_bounds__(256, 2) void gram_atomic_kernel(const float* __restrict__ x,
                                                             float* __restrict__ energy) {
  const int b    = blockIdx.z;
  const int tsel = blockIdx.y;
  const int kk   = blockIdx.x;
  const int ti   = (tsel == 1) ? 1 : 0;
  const int tj   = (tsel == 0) ? 0 : 1;
  const bool diag = (tsel < 2);

  const float* vb    = x + (size_t)b * Cn * Sn;
  const float* Abase = vb + (size_t)(ti * TILE) * Sn + kk * KSLICE;
  const float* Bbase = vb + (size_t)(tj * TILE) * Sn + kk * KSLICE;

  __shared__ __align__(16) __bf16 Ah[TILE * 32];
  __shared__ __align__(16) __bf16 Al[TILE * 32];
  __shared__ __align__(16) __bf16 Bh[TILE * 32];
  __shared__ __align__(16) __bf16 Bl[TILE * 32];

  const int t    = threadIdx.x;
  const int lane = t & 63;
  const int wv   = t >> 6;
  const int wr   = wv >> 1;
  const int wc   = wv & 1;
  const int ln   = lane & 15;
  const int quad = lane >> 4;
  const int srow = t >> 3;
  const int skq  = t & 7;

  float4 areg[4], breg[4];
#pragma unroll
  for (int it = 0; it < 4; it++)
    areg[it] = *(const float4*)(Abase + (size_t)(srow + it * 32) * Sn + skq * 4);
  if (!diag) {
#pragma unroll
    for (int it = 0; it < 4; it++)
      breg[it] = *(const float4*)(Bbase + (size_t)(srow + it * 32) * Sn + skq * 4);
  }

  f32x4 acc[4][4];
#pragma unroll
  for (int i = 0; i < 4; i++)
#pragma unroll
    for (int j = 0; j < 4; j++) acc[i][j] = (f32x4){0.f, 0.f, 0.f, 0.f};

  for (int kc = 0; kc < KSLICE; kc += KB) {
#pragma unroll
    for (int it = 0; it < 4; it++) split_store(Ah, Al, srow + it * 32, skq, areg[it]);
    if (!diag) {
#pragma unroll
      for (int it = 0; it < 4; it++) split_store(Bh, Bl, srow + it * 32, skq, breg[it]);
    }
    __syncthreads();

    const __bf16* PH = diag ? Ah : Bh;
    const __bf16* PL = diag ? Al : Bl;

    bf16x8 fah[4], fal[4];
#pragma unroll
    for (int i = 0; i < 4; i++) {
      int ar = wr * 64 + i * 16 + ln;
      fah[i] = frag_ld(Ah, ar, quad);
      fal[i] = frag_ld(Al, ar, quad);
    }

    if (kc + KB < KSLICE) {
#pragma unroll
      for (int it = 0; it < 4; it++)
        areg[it] = *(const float4*)(Abase + (size_t)(srow + it * 32) * Sn + (kc + KB) + skq * 4);
      if (!diag) {
#pragma unroll
        for (int it = 0; it < 4; it++)
          breg[it] = *(const float4*)(Bbase + (size_t)(srow + it * 32) * Sn + (kc + KB) + skq * 4);
      }
    }

#pragma unroll
    for (int j = 0; j < 4; j++) {
      int br = wc * 64 + j * 16 + ln;
      bf16x8 fbh = frag_ld(PH, br, quad);
      bf16x8 fbl = frag_ld(PL, br, quad);
#pragma unroll
      for (int i = 0; i < 4; i++) {
        acc[i][j] = __builtin_amdgcn_mfma_f32_16x16x32_bf16(fah[i], fbh, acc[i][j], 0, 0, 0);
        acc[i][j] = __builtin_amdgcn_mfma_f32_16x16x32_bf16(fah[i], fbl, acc[i][j], 0, 0, 0);
        acc[i][j] = __builtin_amdgcn_mfma_f32_16x16x32_bf16(fal[i], fbh, acc[i][j], 0, 0, 0);
      }
    }
    __syncthreads();
  }

  float* E = energy + (size_t)b * Cn * Cn;
#pragma unroll
  for (int i = 0; i < 4; i++)
#pragma unroll
    for (int j = 0; j < 4; j++) {
      int c0 = ti * TILE + wr * 64 + i * 16 + quad * 4;
      int d  = tj * TILE + wc * 64 + j * 16 + ln;
#pragma unroll
      for (int r = 0; r < 4; r++) {
        float v = acc[i][j][r];
        atomicAdd(&E[(size_t)(c0 + r) * Cn + d], v);
        if (tsel == 2) atomicAdd(&E[(size_t)d * Cn + (c0 + r)], v);
      }
    }
}

__global__ __launch_bounds__(256) void softmax_kernel(float* __restrict__ energy) {
  const int wv   = threadIdx.x >> 6;
  const int lane = threadIdx.x & 63;
  const int row  = blockIdx.x * 4 + wv;

  float4 e = *(const float4*)&energy[(size_t)row * Cn + lane * 4];
  float m = fminf(fminf(e.x, e.y), fminf(e.z, e.w));
#pragma unroll
  for (int o = 32; o > 0; o >>= 1) m = fminf(m, __shfl_xor(m, o));

  float4 p;
  p.x = expf(m - e.x); p.y = expf(m - e.y);
  p.z = expf(m - e.z); p.w = expf(m - e.w);
  float s = p.x + p.y + p.z + p.w;
#pragma unroll
  for (int o = 32; o > 0; o >>= 1) s += __shfl_xor(s, o);

  float inv = 1.f / s;
  p.x *= inv; p.y *= inv; p.z *= inv; p.w *= inv;
  *(float4*)&energy[(size_t)row * Cn + lane * 4] = p;
}

extern "C" void kernel_launch(void* const* d_in, const int* in_sizes, int n_in,
                              void* d_out, int out_size, void* d_ws, size_t ws_size,
                              hipStream_t stream) {
  const float* x     = (const float*)d_in[0];
  const float* alpha = (const float*)d_in[1];
  float*       out   = (float*)d_out;

  const size_t ecnt  = (size_t)Bn * Cn * Cn;            // 524288 floats (2 MB)
  const size_t pcnt  = (size_t)KSPLIT * ecnt;           // 32 MB of partials
  const size_t need  = (pcnt + ecnt) * sizeof(float);   // 34 MB

  dim3 g1(KSPLIT, 3, Bn);                               // 16 x 3 x 8 = 384 blocks
  dim3 g3(Sn / 128, Cn / 128, Bn);                      // 128 x 2 x 8 = 2048 blocks

  if (ws_size >= need) {
    float* P = (float*)d_ws;                            // [kk][b][c][d]
    float* w = (float*)d_ws + pcnt;                     // softmax output

    gram_part_kernel<<<g1, 256, 0, stream>>>(x, P);
    softmax_reduce_kernel<<<(Bn * Cn) / 4, 256, 0, stream>>>(P, w);
    ygemm_mfma_kernel<<<g3, 256, 0, stream>>>(w, x, alpha, out);
  } else {
    // R3-measured fallback (atomic gram)
    float* energy = (float*)d_ws;
    hipMemsetAsync(energy, 0, ecnt * sizeof(float), stream);
    gram_atomic_kernel<<<g1, 256, 0, stream>>>(x, energy);
    softmax_kernel<<<(Bn * Cn) / 4, 256, 0, stream>>>(energy);
    ygemm_mfma_kernel<<<g3, 256, 0, stream>>>(energy, x, alpha, out);
  }
}